// Round 2
// baseline (711.128 us; speedup 1.0000x reference)
//
#include <hip/hip_runtime.h>
#include <cstdint>
#include <cstddef>

#define C_DIM 768
#define N_DIM 16384

typedef __attribute__((ext_vector_type(8))) short short8;   // 8 bf16 = 4 VGPRs
typedef __attribute__((ext_vector_type(4))) float f32x4;

__device__ __forceinline__ ushort f2bf(float f) {
    uint32_t u = __float_as_uint(f);
    uint32_t r = 0x7fffu + ((u >> 16) & 1u);   // round-to-nearest-even
    return (ushort)((u + r) >> 16);
}

__device__ __forceinline__ void async_ld16(const void* g, void* l) {
    __builtin_amdgcn_global_load_lds(
        (__attribute__((address_space(1))) void*)g,
        (__attribute__((address_space(3))) void*)l,
        16, 0, 0);
}

// ---------------------------------------------------------------------------
// Normalize columns of F (C_DIM x N_DIM) and write transposed bf16:
// T[i][c] = F[c][i] / max(||col_i||, eps).  blockIdx.y selects the input.
// (verified rounds 1-4; unchanged)
// ---------------------------------------------------------------------------
__global__ __launch_bounds__(256) void norm_tr(const float* __restrict__ F0,
                                               ushort* __restrict__ T0,
                                               const float* __restrict__ F1,
                                               ushort* __restrict__ T1) {
    const float*  F = blockIdx.y ? F1 : F0;
    ushort*       T = blockIdx.y ? T1 : T0;
    const int i0 = blockIdx.x * 64;
    const int t  = threadIdx.x;
    const int tx = t & 63;
    const int ty = t >> 6;

    float ss = 0.f;
    for (int c = ty; c < C_DIM; c += 4) {
        float v = F[(size_t)c * N_DIM + i0 + tx];
        ss += v * v;
    }
    __shared__ float red[4][64];
    __shared__ float scale[64];
    red[ty][tx] = ss;
    __syncthreads();
    if (t < 64) {
        float s = red[0][t] + red[1][t] + red[2][t] + red[3][t];
        float n = sqrtf(s);
        scale[t] = 1.0f / fmaxf(n, 1e-12f);
    }
    __syncthreads();

    __shared__ float tile[64][65];
    const int i_l   = t >> 3;
    const int c_off = (t & 7) * 8;
    for (int c0 = 0; c0 < C_DIM; c0 += 64) {
        #pragma unroll
        for (int rr = 0; rr < 16; ++rr) {
            int c_l = rr * 4 + ty;
            tile[c_l][tx] = F[(size_t)(c0 + c_l) * N_DIM + i0 + tx] * scale[tx];
        }
        __syncthreads();
        #pragma unroll
        for (int half = 0; half < 2; ++half) {
            int il = i_l + half * 32;
            __align__(16) ushort pack[8];
            #pragma unroll
            for (int j = 0; j < 8; ++j)
                pack[j] = f2bf(tile[c_off + j][il]);
            *(uint4*)&T[(size_t)(i0 + il) * C_DIM + c0 + c_off] = *(const uint4*)pack;
        }
        __syncthreads();
    }
}

// ---------------------------------------------------------------------------
// Fused GEMM + row-max.  Round-5: identical tile/addressing to the verified
// 684us baseline (128x256 block, 512 thr / 8 waves, 48KB dbuf LDS, XOR bank
// swizzle = 0 conflicts, XCD-aware n-slicing).  ONLY the loop sync changed:
//   baseline:  __syncthreads() per iter  -> compiler emits s_waitcnt
//              vmcnt(0) lgkmcnt(0) before s_barrier = full drain of the
//              global_load_lds queue every K-step (MfmaUtil 32%).
//   now (T4):  stage(k+1) FIRST, then asm vmcnt(3) (waits only tile k;
//              tile k+1's 3 loads stay in flight ACROSS the barrier),
//              raw s_barrier, compute, lgkmcnt(0)+raw barrier (protects
//              the stage-after-read of buf^1).  Last iter peeled (vmcnt(0),
//              no stage) so nothing is outstanding at endpgm.
// Ledger: iter k entry = 3 loads (tile k) outstanding; +3 issued; vmcnt(3)
// retires exactly tile k.  buf^1's reads drained at iter k-1's tail barrier.
// ---------------------------------------------------------------------------
__global__ __launch_bounds__(512) void gemm_rowmax(const ushort* __restrict__ A,
                                                   const ushort* __restrict__ B,
                                                   unsigned* __restrict__ rowkey) {
    __shared__ __align__(16) ushort As[2][128 * 32];   // 16 KB
    __shared__ __align__(16) ushort Bs[2][256 * 32];   // 32 KB

    const int t    = threadIdx.x;
    const int lane = t & 63;
    const int w    = t >> 6;          // 0..7
    const int wm   = w >> 2;          // 0..1  (64-row half)
    const int wn   = w & 3;           // 0..3  (64-col quarter)

    // XCD-aware mapping: xcd owns an 8-tile n-slice (2048 cols, 3MB of B in
    // its L2); n fastest so A-tiles get 8x L2 reuse across consecutive blocks.
    const int bid   = blockIdx.x;
    const int xcd   = bid & 7;
    const int local = bid >> 3;                     // 0..1023
    const int m0    = (local >> 3) * 128;           // 128 m-tiles
    const int n0    = (xcd * 8 + (local & 7)) * 256;

    f32x4 acc[4][4];
    #pragma unroll
    for (int i = 0; i < 4; ++i)
        #pragma unroll
        for (int j = 0; j < 4; ++j)
            acc[i][j] = (f32x4){0.f, 0.f, 0.f, 0.f};

    // staging: thread t -> row t>>2, phys 16B chunk t&3 at LDS byte t*16;
    // logical k-quad XOR-swizzled by row bits 1-2 (verified 0 conflicts).
    // B second issue covers rows 128..255: (row>>1)&3 == (t>>3)&3 still.
    const int kq = ((t & 3) ^ ((t >> 3) & 3)) * 8;
    const ushort* ag  = A + (size_t)(m0 + (t >> 2)) * C_DIM + kq;
    const ushort* bg0 = B + (size_t)(n0 + (t >> 2)) * C_DIM + kq;
    const ushort* bg1 = bg0 + (size_t)128 * C_DIM;
    const int lda = t * 8;                 // element offsets into As/Bs
    const int ldb0 = t * 8, ldb1 = 128 * 32 + t * 8;

    // fragment reads: logical k-quad x = lane>>4 lives at quadpos
    // x ^ ((row>>1)&3); row = base + (lane&15), base % 16 == 0.
    const int qp    = ((lane >> 4) ^ ((lane >> 1) & 3)) * 8;
    const int a_off = (wm * 64 + (lane & 15)) * 32 + qp;
    const int b_off = (wn * 64 + (lane & 15)) * 32 + qp;

    // prologue: stage tile k=0 into buffer 0 (3 loads outstanding)
    async_ld16(ag,  As[0] + lda);
    async_ld16(bg0, Bs[0] + ldb0);
    async_ld16(bg1, Bs[0] + ldb1);

    int buf = 0;
    for (int k0 = 0; k0 < C_DIM - 32; k0 += 32) {
        // stage tile k+1 into buf^1 (its reads drained at prev iter's tail
        // barrier); issued BEFORE the wait so 3 loads ride across the barrier
        const int kn = k0 + 32, nb = buf ^ 1;
        async_ld16(ag + kn,  As[nb] + lda);
        async_ld16(bg0 + kn, Bs[nb] + ldb0);
        async_ld16(bg1 + kn, Bs[nb] + ldb1);

        asm volatile("s_waitcnt vmcnt(3)" ::: "memory");   // tile k landed
        __builtin_amdgcn_s_barrier();

        const ushort* Ab = As[buf];
        const ushort* Bb = Bs[buf];
        short8 af[4], bfr[4];
        #pragma unroll
        for (int mt = 0; mt < 4; ++mt)
            af[mt] = *(const short8*)(Ab + a_off + mt * 16 * 32);
        #pragma unroll
        for (int nt = 0; nt < 4; ++nt)
            bfr[nt] = *(const short8*)(Bb + b_off + nt * 16 * 32);

        __builtin_amdgcn_s_setprio(1);
        #pragma unroll
        for (int mt = 0; mt < 4; ++mt)
            #pragma unroll
            for (int nt = 0; nt < 4; ++nt)
                acc[mt][nt] = __builtin_amdgcn_mfma_f32_16x16x32_bf16(
                    af[mt], bfr[nt], acc[mt][nt], 0, 0, 0);
        __builtin_amdgcn_s_setprio(0);

        // all reads of buf drained before any wave stages into it next iter
        asm volatile("s_waitcnt lgkmcnt(0)" ::: "memory");
        __builtin_amdgcn_s_barrier();
        buf ^= 1;
    }

    // peeled final K-step: nothing left to stage; tile 23 (3 loads) is the
    // only outstanding -> vmcnt(0) is exact, and endpgm is clean.
    {
        asm volatile("s_waitcnt vmcnt(0)" ::: "memory");
        __builtin_amdgcn_s_barrier();
        const ushort* Ab = As[buf];
        const ushort* Bb = Bs[buf];
        short8 af[4], bfr[4];
        #pragma unroll
        for (int mt = 0; mt < 4; ++mt)
            af[mt] = *(const short8*)(Ab + a_off + mt * 16 * 32);
        #pragma unroll
        for (int nt = 0; nt < 4; ++nt)
            bfr[nt] = *(const short8*)(Bb + b_off + nt * 16 * 32);
        __builtin_amdgcn_s_setprio(1);
        #pragma unroll
        for (int mt = 0; mt < 4; ++mt)
            #pragma unroll
            for (int nt = 0; nt < 4; ++nt)
                acc[mt][nt] = __builtin_amdgcn_mfma_f32_16x16x32_bf16(
                    af[mt], bfr[nt], acc[mt][nt], 0, 0, 0);
        __builtin_amdgcn_s_setprio(0);
    }

    // epilogue: per-row max over this wave's 64 columns; waves sharing the
    // same m-rows (wn 0..3) merge via device-scope atomicMax.
    // C/D layout: col = lane&15, row = (lane>>4)*4 + reg.
    #pragma unroll
    for (int mt = 0; mt < 4; ++mt) {
        #pragma unroll
        for (int reg = 0; reg < 4; ++reg) {
            float v = fmaxf(fmaxf(acc[mt][0][reg], acc[mt][1][reg]),
                            fmaxf(acc[mt][2][reg], acc[mt][3][reg]));
            #pragma unroll
            for (int off = 1; off < 16; off <<= 1)
                v = fmaxf(v, __shfl_xor(v, off, 64));
            if ((lane & 15) == 0) {
                int m = m0 + wm * 64 + mt * 16 + (lane >> 4) * 4 + reg;
                unsigned u = __float_as_uint(v);
                u = (u & 0x80000000u) ? ~u : (u | 0x80000000u);  // order-preserving
                atomicMax(&rowkey[m], u);
            }
        }
    }
}

// ---------------------------------------------------------------------------
// Final: loss = 1 - mean(rowmax)
// ---------------------------------------------------------------------------
__global__ __launch_bounds__(1024) void finalize(const unsigned* __restrict__ rowkey,
                                                 float* __restrict__ out) {
    const int t = threadIdx.x;
    float s = 0.f;
    for (int i = t; i < N_DIM; i += 1024) {
        unsigned u = rowkey[i];
        float f = (u & 0x80000000u) ? __uint_as_float(u ^ 0x80000000u)
                                    : __uint_as_float(~u);
        s += f;
    }
    #pragma unroll
    for (int off = 32; off >= 1; off >>= 1)
        s += __shfl_down(s, off, 64);
    __shared__ float part[16];
    if ((t & 63) == 0) part[t >> 6] = s;
    __syncthreads();
    if (t == 0) {
        float tot = 0.f;
        #pragma unroll
        for (int i = 0; i < 16; ++i) tot += part[i];
        out[0] = 1.0f - tot * (1.0f / (float)N_DIM);
    }
}

extern "C" void kernel_launch(void* const* d_in, const int* in_sizes, int n_in,
                              void* d_out, int out_size, void* d_ws, size_t ws_size,
                              hipStream_t stream) {
    const float* F_r = (const float*)d_in[0];
    const float* F_s = (const float*)d_in[1];

    ushort*   Rt     = (ushort*)d_ws;                       // 16384 x 768 bf16
    ushort*   St     = Rt + (size_t)N_DIM * C_DIM;          // 16384 x 768 bf16
    unsigned* rowkey = (unsigned*)(St + (size_t)N_DIM * C_DIM);  // 16384 u32
    float*    out    = (float*)d_out;

    hipLaunchKernelGGL(norm_tr, dim3(N_DIM / 64, 2), dim3(256), 0, stream,
                       F_r, Rt, F_s, St);
    hipMemsetAsync(rowkey, 0, N_DIM * sizeof(unsigned), stream);
    hipLaunchKernelGGL(gemm_rowmax, dim3((N_DIM / 128) * (N_DIM / 256)), dim3(512),
                       0, stream, Rt, St, rowkey);
    hipLaunchKernelGGL(finalize, dim3(1), dim3(1024), 0, stream, rowkey, out);
}